// Round 13
// baseline (298.878 us; speedup 1.0000x reference)
//
#include <hip/hip_runtime.h>
#include <hip/hip_fp16.h>

typedef _Float16 f16;
typedef f16 f16x8 __attribute__((ext_vector_type(8)));
typedef f16 f16x4 __attribute__((ext_vector_type(4)));
typedef float f32x4 __attribute__((ext_vector_type(4)));

constexpr int Bb = 8, Cc = 1024, Tt = 2048, Ci = 512;
constexpr float BN_EPS = 1e-5f;

__device__ __forceinline__ void gload16(const f16* g, f16* l) {
  __builtin_amdgcn_global_load_lds(
      (const __attribute__((address_space(1))) void*)g,
      (__attribute__((address_space(3))) void*)l, 16, 0, 0);
}

// ---------------- fp32 -> fp16 convert (weights) ----------------
__global__ __launch_bounds__(256)
void cvt_kernel(const float* __restrict__ src, f16* __restrict__ dst, int n4) {
  int i = blockIdx.x * blockDim.x + threadIdx.x;
  if (i < n4) {
    float4 v = *((const float4*)src + i);
    f16x4 h;
    h[0] = (f16)v.x; h[1] = (f16)v.y; h[2] = (f16)v.z; h[3] = (f16)v.w;
    *((f16x4*)dst + i) = h;
  }
}

// ---------------- transpose-convert: x[b][c][t] f32 -> xT[b][t][c] f16 ----
__global__ __launch_bounds__(256)
void cvtT_kernel(const float* __restrict__ x, f16* __restrict__ xT) {
  __shared__ float tile[64][68];
  const int b = blockIdx.z, c0 = blockIdx.y * 64, t0 = blockIdx.x * 64;
  const int tid = threadIdx.x;
  const float* xp = x + ((long)b * Cc + c0) * Tt + t0;
  {
    int r = tid >> 4, c4 = (tid & 15) * 4;
    #pragma unroll
    for (int it = 0; it < 4; it++) {
      float4 v = *(const float4*)(xp + (long)(r + it * 16) * Tt + c4);
      *(float4*)&tile[r + it * 16][c4] = v;
    }
  }
  __syncthreads();
  f16* op = xT + ((long)b * Tt + t0) * Cc + c0;
  {
    int c8 = (tid & 7) * 8;
    #pragma unroll
    for (int it = 0; it < 2; it++) {
      int t = (tid >> 3) + it * 32;
      f16x8 o;
      #pragma unroll
      for (int jj = 0; jj < 8; jj++) o[jj] = (f16)tile[c8 + jj][t];
      *(f16x8*)(op + (long)t * Cc + c8) = o;
    }
  }
}

// ======== 256x256 BK=64 8-PHASE GEMM (m201 template port, f16) =============
// C[m][n] = sum_k A[m][k]*B[n][k]. 8 waves as 2M x 4N (wave tile 128x64).
// LDS 128 KiB: 2 bufs x {A 32KB + B 32KB}; each matrix split into 2 ks-halves
// (256 rows x 32 k = 16KB = 2 gloads/thread). K-major 16B chunks: chunk
// (khi,row) at (ks*4+khi)*256+row -> conflict-free ds_read_b128.
// Per phase: {ds_read subtile || stage 1 ks-half} -> barrier -> lgkmcnt(0)
// -> setprio(1) 16 MFMA setprio(0) -> [vmcnt(4) at ph4/ph8] -> barrier.
// Staging order (iter i computes T=2i buf0 ph1-4, T+1 buf1 ph5-8):
//  ph1:A1(T+1) ph2:B1(T+1) ph3:A0(T+2) ph4:B0(T+2) ph5:A1(T+2) ph6:B1(T+2)
//  ph7:A0(T+3) ph8:B0(T+3)  -- each stage targets a region whose readers
//  retired at a previous phase's closing barrier (verified).
// BIAS_MODE: 0 none, 1 per-m, 2 per-n. DO_MAX: per-column max -> gmax.
template<int BIAS_MODE, bool DO_MAX>
__global__ __launch_bounds__(512, 2)
void gemm8ph(const f16* __restrict__ A, const f16* __restrict__ B,
             f16* __restrict__ C, const float* __restrict__ bias,
             unsigned* __restrict__ gmax,
             int K, int lda, int ldb, int ldc, long sA, long sB, long sC,
             int nx, int ny)
{
  extern __shared__ f16 lds[];     // 2 x 32768 halves
  // XCD-aware bijective swizzle (grid %8==0), z-major decode
  const int per = gridDim.x >> 3;
  const int nid = (blockIdx.x & 7) * per + (blockIdx.x >> 3);
  const int bz = nid / (nx * ny);
  const int rem = nid - bz * nx * ny;
  const int by = rem / nx, bx = rem - by * nx;

  const int tid = threadIdx.x, lane = tid & 63, wv = tid >> 6;
  const int bm0 = by * 256, bn0 = bx * 256;
  const int wm = wv >> 2, wn = wv & 3;          // 2M x 4N
  const f16* Ab = A + (long)bz * sA + (long)bm0 * lda;
  const f16* Bt = B + (long)bz * sB + (long)bn0 * ldb;
  C += (long)bz * sC;
  const int r16 = lane & 15, khl = lane >> 4;

  // stage one ks-half of A/B (2 gloads per thread); linear LDS dest
  auto stA = [&](int buf, int ks, int k0) {
    #pragma unroll
    for (int r = 0; r < 2; r++) {
      int id = r * 512 + tid;
      gload16(Ab + (long)(id & 255) * lda + k0 + ks * 32 + (id >> 8) * 8,
              lds + buf * 32768 + ks * 8192 + (r * 512 + wv * 64) * 8);
    }
  };
  auto stB = [&](int buf, int ks, int k0) {
    #pragma unroll
    for (int r = 0; r < 2; r++) {
      int id = r * 512 + tid;
      gload16(Bt + (long)(id & 255) * ldb + k0 + ks * 32 + (id >> 8) * 8,
              lds + buf * 32768 + 16384 + ks * 8192 + (r * 512 + wv * 64) * 8);
    }
  };

  const int aB = khl * 2048 + (wm * 128 + r16) * 8;           // halves
  const int bB = 16384 + khl * 2048 + (wn * 64 + r16) * 8;

  f32x4 acc[8][4] = {};
  const int ni = K >> 7;                        // iterations of 2 K-tiles

  // prologue: T0 complete (A0,B0,A1,B1), T1 ks0 (A0,B0)
  stA(0, 0, 0); stB(0, 0, 0); stA(0, 1, 0); stB(0, 1, 0);
  stA(1, 0, 64); stB(1, 0, 64);
  asm volatile("s_waitcnt vmcnt(4)" ::: "memory");            // T0 landed
  __builtin_amdgcn_s_barrier();

  f16x8 af[4], bf[4];

#define RD_A(buf, ks, mi0) { _Pragma("unroll") for (int m = 0; m < 4; m++) \
    af[m] = *(const f16x8*)(lds + (buf) * 32768 + (ks) * 8192 + aB + (mi0 + m) * 128); }
#define RD_B(buf, ks) { _Pragma("unroll") for (int n = 0; n < 4; n++) \
    bf[n] = *(const f16x8*)(lds + (buf) * 32768 + (ks) * 8192 + bB + n * 128); }
#define BAR1 __builtin_amdgcn_s_barrier(); \
    asm volatile("s_waitcnt lgkmcnt(0)" ::: "memory"); \
    __builtin_amdgcn_sched_barrier(0);
#define MM(mi0) __builtin_amdgcn_s_setprio(1); \
    { _Pragma("unroll") for (int m = 0; m < 4; m++) { _Pragma("unroll") for (int n = 0; n < 4; n++) \
        acc[mi0 + m][n] = __builtin_amdgcn_mfma_f32_16x16x32_f16(af[m], bf[n], acc[mi0 + m][n], 0, 0, 0); } } \
    __builtin_amdgcn_s_setprio(0);
#define BAR2 __builtin_amdgcn_s_barrier();

  for (int i = 0; i < ni; i++) {
    const int k1 = (2 * i + 1) << 6, k2 = (2 * i + 2) << 6, k3 = (2 * i + 3) << 6;
    const bool more = (i + 1) < ni;
    // ph1: compute T ks0 mi0-3
    RD_A(0, 0, 0); RD_B(0, 0);
    stA(1, 1, k1);
    BAR1; MM(0); BAR2;
    // ph2: T ks0 mi4-7 (bf reused)
    RD_A(0, 0, 4);
    stB(1, 1, k1);
    BAR1; MM(4); BAR2;
    // ph3: T ks1 mi0-3
    RD_A(0, 1, 0); RD_B(0, 1);
    if (more) stA(0, 0, k2);
    BAR1; MM(0); BAR2;
    // ph4: T ks1 mi4-7; counted wait -> T+1 complete
    RD_A(0, 1, 4);
    if (more) stB(0, 0, k2);
    BAR1; MM(4);
    if (more) asm volatile("s_waitcnt vmcnt(4)" ::: "memory");
    else      asm volatile("s_waitcnt vmcnt(0)" ::: "memory");
    BAR2;
    // ph5: T+1 ks0 mi0-3
    RD_A(1, 0, 0); RD_B(1, 0);
    if (more) stA(0, 1, k2);
    BAR1; MM(0); BAR2;
    // ph6: T+1 ks0 mi4-7
    RD_A(1, 0, 4);
    if (more) stB(0, 1, k2);
    BAR1; MM(4); BAR2;
    // ph7: T+1 ks1 mi0-3
    RD_A(1, 1, 0); RD_B(1, 1);
    if (more) stA(1, 0, k3);
    BAR1; MM(0); BAR2;
    // ph8: T+1 ks1 mi4-7; counted wait -> T+2 complete
    RD_A(1, 1, 4);
    if (more) stB(1, 0, k3);
    BAR1; MM(4);
    if (more) asm volatile("s_waitcnt vmcnt(4)" ::: "memory");
    BAR2;
  }
#undef RD_A
#undef RD_B
#undef BAR1
#undef MM
#undef BAR2

  // ---- epilogue (fused per-column max for DO_MAX) ----
  const int rg = khl * 4;
  float cmx[4] = {-3e38f, -3e38f, -3e38f, -3e38f};
  #pragma unroll
  for (int mi = 0; mi < 8; mi++) {
    const int row0 = bm0 + wm * 128 + mi * 16 + rg;
    #pragma unroll
    for (int r = 0; r < 4; r++) {
      const int row = row0 + r;
      const float br = (BIAS_MODE == 1) ? bias[row] : 0.0f;
      #pragma unroll
      for (int nj = 0; nj < 4; nj++) {
        const int col = bn0 + wn * 64 + nj * 16 + r16;
        float v = acc[mi][nj][r] + ((BIAS_MODE == 2) ? bias[col] : br);
        C[(long)row * ldc + col] = (f16)v;
        if (DO_MAX) cmx[nj] = fmaxf(cmx[nj], v);
      }
    }
  }
  if (DO_MAX) {
    #pragma unroll
    for (int nj = 0; nj < 4; nj++) {
      float mx = cmx[nj];
      mx = fmaxf(mx, __shfl_xor(mx, 16));
      mx = fmaxf(mx, __shfl_xor(mx, 32));
      if (khl == 0) {
        const int col = bn0 + wn * 64 + nj * 16 + r16;
        unsigned u = __float_as_uint(mx);
        unsigned key = (u & 0x80000000u) ? ~u : (u | 0x80000000u);
        atomicMax(gmax + (long)bz * ldc + col, key);
      }
    }
  }
}

// ======== r10 256x128 BK=32 ring-3 GEMM (V-proj / PV), 2 blocks/CU =========
template<int BIAS_MODE, bool DO_MAX>
__global__ __launch_bounds__(512, 2)
void gemm8p(const f16* __restrict__ A, const f16* __restrict__ B,
            f16* __restrict__ C, const float* __restrict__ bias,
            unsigned* __restrict__ gmax,
            int K, int lda, int ldb, int ldc, long sA, long sB, long sC,
            int nx, int ny)
{
  extern __shared__ f16 lds[];
  constexpr int TILE_A = 256 * 32;
  constexpr int TILE_B = 128 * 32;
  constexpr int TILE   = TILE_A + TILE_B;

  const int per = gridDim.x >> 3;
  const int nid = (blockIdx.x & 7) * per + (blockIdx.x >> 3);
  const int bz = nid / (nx * ny);
  const int rem = nid - bz * nx * ny;
  const int by = rem / nx, bx = rem - by * nx;

  const int tid = threadIdx.x, lane = tid & 63, wv = tid >> 6;
  const int bm0 = by * 256, bn0 = bx * 128;
  const int wm = (wv >> 1) * 64, wn = (wv & 1) * 64;
  const f16* Ab = A + (long)bz * sA + (long)bm0 * lda;
  const f16* Bt = B + (long)bz * sB + (long)bn0 * ldb;
  C += (long)bz * sC;

  const int r16 = lane & 15, khi = lane >> 4;

  auto stA = [&](int slot, int k0, int r) {
    int L = (r * 512 + tid) * 16;
    int G = L ^ (((L >> 7) & 3) << 4);
    gload16(Ab + (long)(G >> 6) * lda + k0 + ((G & 63) >> 1),
            lds + (long)slot * TILE + (r * 512 + wv * 64) * 8);
  };
  auto stB = [&](int slot, int k0) {
    int L = tid * 16;
    int G = L ^ (((L >> 7) & 3) << 4);
    gload16(Bt + (long)(G >> 6) * ldb + k0 + ((G & 63) >> 1),
            lds + (long)slot * TILE + TILE_A + (wv * 64) * 8);
  };

  f32x4 acc[4][4] = {};
  const int nt = K >> 5;

  stA(0, 0, 0); stA(0, 0, 1); stB(0, 0);
  stA(1, 32, 0); stA(1, 32, 1); stB(1, 32);
  asm volatile("s_waitcnt vmcnt(3)" ::: "memory");
  __builtin_amdgcn_s_barrier();

  for (int t = 0; t < nt; t++) {
    const int slot = t % 3;
    const int nslot = (t + 2) % 3;
    const int k2 = (t + 2) << 5;
    const bool st = (t + 2) < nt;
    const char* baseA = (const char*)(lds + (long)slot * TILE);
    const char* baseB = (const char*)(lds + (long)slot * TILE + TILE_A);

    if (st) { stA(nslot, k2, 0); stA(nslot, k2, 1); stB(nslot, k2); }

    f16x8 af[4], bf[4];
    #pragma unroll
    for (int i = 0; i < 4; i++) {
      const int row = wm + i * 16 + r16;
      af[i] = *(const f16x8*)(baseA + (((row << 6) + (khi << 4)) ^ (((row >> 1) & 3) << 4)));
    }
    #pragma unroll
    for (int j = 0; j < 4; j++) {
      const int row = wn + j * 16 + r16;
      bf[j] = *(const f16x8*)(baseB + (((row << 6) + (khi << 4)) ^ (((row >> 1) & 3) << 4)));
    }

    __builtin_amdgcn_s_setprio(1);
    #pragma unroll
    for (int i = 0; i < 4; i++)
      #pragma unroll
      for (int j = 0; j < 4; j++)
        acc[i][j] = __builtin_amdgcn_mfma_f32_16x16x32_f16(af[i], bf[j], acc[i][j], 0, 0, 0);
    __builtin_amdgcn_s_setprio(0);

    __builtin_amdgcn_sched_barrier(0);
    if (st) asm volatile("s_waitcnt vmcnt(3)" ::: "memory");
    else    asm volatile("s_waitcnt vmcnt(0)" ::: "memory");
    __builtin_amdgcn_s_barrier();
  }

  const int rg = khi * 4;
  float cmx[4] = {-3e38f, -3e38f, -3e38f, -3e38f};
  #pragma unroll
  for (int i = 0; i < 4; i++) {
    const int row0 = bm0 + wm + i * 16 + rg;
    #pragma unroll
    for (int r = 0; r < 4; r++) {
      const int row = row0 + r;
      const float br = (BIAS_MODE == 1) ? bias[row] : 0.0f;
      #pragma unroll
      for (int j = 0; j < 4; j++) {
        const int col = bn0 + wn + j * 16 + r16;
        float v = acc[i][j][r] + ((BIAS_MODE == 2) ? bias[col] : br);
        C[(long)row * ldc + col] = (f16)v;
        if (DO_MAX) cmx[j] = fmaxf(cmx[j], v);
      }
    }
  }
  if (DO_MAX) {
    #pragma unroll
    for (int j = 0; j < 4; j++) {
      float mx = cmx[j];
      mx = fmaxf(mx, __shfl_xor(mx, 16));
      mx = fmaxf(mx, __shfl_xor(mx, 32));
      if (khi == 0) {
        const int col = bn0 + wn + j * 16 + r16;
        unsigned u = __float_as_uint(mx);
        unsigned key = (u & 0x80000000u) ? ~u : (u | 0x80000000u);
        atomicMax(gmax + (long)bz * ldc + col, key);
      }
    }
  }
}

// ---------------- colsum: E = exp(Sq - m[kt]) in place; sums[kt] += ------
__global__ __launch_bounds__(256)
void colsum_kernel(f16* __restrict__ E, const unsigned* __restrict__ gmax,
                   float* __restrict__ sums) {
  const int b = blockIdx.z;
  const int kt = blockIdx.x * 256 + threadIdx.x;
  const long q0 = (long)blockIdx.y * 128;
  unsigned key = gmax[b * Tt + kt];
  float m = (key & 0x80000000u) ? __uint_as_float(key ^ 0x80000000u)
                                : __uint_as_float(~key);
  f16* p = E + ((long)b * Tt + q0) * Tt + kt;
  float s = 0.f;
  #pragma unroll 4
  for (int q = 0; q < 128; q++) {
    float e = __expf((float)p[(long)q * Tt] - m);
    p[(long)q * Tt] = (f16)e;
    s += e;
  }
  atomicAdd(sums + b * Tt + kt, s);
}

// ---------------- vscale: Vt[b][c][kt] *= 1/sums[b][kt] (in place) --------
__global__ __launch_bounds__(256)
void vscale_kernel(f16* __restrict__ Vt, const float* __restrict__ sums) {
  long i = ((long)blockIdx.x * 256 + threadIdx.x) * 8;
  int kt = (int)(i & (Tt - 1));
  int b = (int)(i >> 20);                 // Ci*Tt = 2^20
  f16x8 v = *(f16x8*)(Vt + i);
  const float* sp = sums + b * Tt + kt;
  #pragma unroll
  for (int j = 0; j < 8; j++)
    v[j] = (f16)((float)v[j] * __fdividef(1.0f, sp[j]));
  *(f16x8*)(Vt + i) = v;
}

// ---------------- BN stats per channel over (b,t) --------------------------
__global__ __launch_bounds__(256)
void bnstat_kernel(const f16* __restrict__ wy, float* __restrict__ bsum,
                   float* __restrict__ bsq) {
  const int c = blockIdx.x, tid = threadIdx.x;
  float s1 = 0.f, s2 = 0.f;
  for (int b = 0; b < Bb; b++) {
    f16x8 v = *((const f16x8*)(wy + ((long)b * Cc + c) * Tt) + tid);
    #pragma unroll
    for (int jj = 0; jj < 8; jj++) { float f = (float)v[jj]; s1 += f; s2 += f * f; }
  }
  #pragma unroll
  for (int off = 1; off < 64; off <<= 1) {
    s1 += __shfl_xor(s1, off);
    s2 += __shfl_xor(s2, off);
  }
  __shared__ float l1[4], l2[4];
  const int w = tid >> 6;
  if ((tid & 63) == 0) { l1[w] = s1; l2[w] = s2; }
  __syncthreads();
  if (tid == 0) {
    bsum[c] = (l1[0] + l1[1]) + (l1[2] + l1[3]);
    bsq[c]  = (l2[0] + l2[1]) + (l2[2] + l2[3]);
  }
}

// ---------------- finalize: BN + residual ----------------------------------
__global__ __launch_bounds__(256)
void final_kernel(const f16* __restrict__ wy, const float* __restrict__ x,
                  const float* __restrict__ gamma, const float* __restrict__ beta,
                  const float* __restrict__ bsum, const float* __restrict__ bsq,
                  float* __restrict__ out)
{
  long i = ((long)blockIdx.x * blockDim.x + threadIdx.x) * 4;
  int c = (int)((i >> 11) & (Cc - 1));
  const float cnt = (float)Bb * (float)Tt;
  float mean = bsum[c] / cnt;
  float var  = bsq[c] / cnt - mean * mean;
  float sc = rsqrtf(var + BN_EPS) * gamma[c];
  float sh = beta[c] - mean * sc;
  f16x4 w = *(const f16x4*)(wy + i);
  float4 xv = *(const float4*)(x + i);
  float4 o;
  o.x = (float)w[0] * sc + sh + xv.x;
  o.y = (float)w[1] * sc + sh + xv.y;
  o.z = (float)w[2] * sc + sh + xv.z;
  o.w = (float)w[3] * sc + sh + xv.w;
  *(float4*)(out + i) = o;
}

// ---------------- host launch ----------------
extern "C" void kernel_launch(void* const* d_in, const int* in_sizes, int n_in,
                              void* d_out, int out_size, void* d_ws, size_t ws_size,
                              hipStream_t stream) {
  const float* x    = (const float*)d_in[0];
  const float* Wq_w = (const float*)d_in[1];
  const float* Wq_b = (const float*)d_in[2];
  const float* Wk_w = (const float*)d_in[3];
  const float* Wk_b = (const float*)d_in[4];
  const float* Wv_w = (const float*)d_in[5];
  const float* Wv_b = (const float*)d_in[6];
  const float* Wo_w = (const float*)d_in[7];
  const float* Wo_b = (const float*)d_in[8];
  const float* gamma = (const float*)d_in[9];
  const float* beta  = (const float*)d_in[10];
  float* out = (float*)d_out;

  constexpr long SZ_XT = (long)Bb * Tt * Cc;   // 16,777,216
  constexpr long SZ_Q  = (long)Bb * Tt * Ci;   // 8,388,608
  constexpr long SZ_S  = (long)Bb * Tt * Tt;   // 33,554,432
  constexpr long SZ_W  = (long)Ci * Cc;        // 524,288

  f16* ws = (f16*)d_ws;
  f16* xT  = ws;                // [B][T][C]
  f16* QK  = xT + SZ_XT;        // [B][T][1024]: Q cols 0-511, K cols 512-1023
  f16* Vt  = QK + SZ_XT;        // [B][Ci][T]
  f16* Sq  = Vt + SZ_Q;         // [B][Tq][Tk] -> exp'd in place by colsum
  f16* Y   = Sq + SZ_S;         // [B][Tq][Ci]
  f16* wy  = Y + SZ_Q;          // [B][C][T]
  f16* wqk = wy + SZ_XT;        // [1024][1024] stacked Wq||Wk
  f16* wv  = wqk + 2 * SZ_W;
  f16* wo  = wv + SZ_W;
  unsigned* gmax = (unsigned*)(wo + SZ_W);     // [B*Tt] encoded col max
  float* sums = (float*)(gmax + (long)Bb * Tt);// [B*Tt]
  float* bsum = sums + (long)Bb * Tt;          // [Cc]
  float* bsq  = bsum + Cc;                     // [Cc]
  float* qkb  = bsq + Cc;                      // [1024] concat bias

  constexpr int LDSB  = (256 * 32 + 128 * 32) * 3 * 2; // 73728 B (gemm8p)
  constexpr int LDSB8 = 2 * 32768 * 2;                 // 131072 B (gemm8ph)
  hipFuncSetAttribute(reinterpret_cast<const void*>(gemm8ph<2, false>),
                      hipFuncAttributeMaxDynamicSharedMemorySize, LDSB8);
  hipFuncSetAttribute(reinterpret_cast<const void*>(gemm8ph<1, false>),
                      hipFuncAttributeMaxDynamicSharedMemorySize, LDSB8);
  hipFuncSetAttribute(reinterpret_cast<const void*>(gemm8ph<0, true>),
                      hipFuncAttributeMaxDynamicSharedMemorySize, LDSB8);
  hipFuncSetAttribute(reinterpret_cast<const void*>(gemm8p<1, false>),
                      hipFuncAttributeMaxDynamicSharedMemorySize, LDSB);
  hipFuncSetAttribute(reinterpret_cast<const void*>(gemm8p<0, false>),
                      hipFuncAttributeMaxDynamicSharedMemorySize, LDSB);

  // zero accumulators (gmax||sums contiguous)
  hipMemsetAsync(gmax, 0, (long)Bb * Tt * 2 * sizeof(float), stream);
  // concat q/k bias
  hipMemcpyAsync(qkb, Wq_b, Ci * sizeof(float), hipMemcpyDeviceToDevice, stream);
  hipMemcpyAsync(qkb + Ci, Wk_b, Ci * sizeof(float), hipMemcpyDeviceToDevice, stream);

  // weight converts (wq||wk stacked)
  cvt_kernel<<<(int)(SZ_W / 4 / 256), 256, 0, stream>>>(Wq_w, wqk, (int)(SZ_W / 4));
  cvt_kernel<<<(int)(SZ_W / 4 / 256), 256, 0, stream>>>(Wk_w, wqk + SZ_W, (int)(SZ_W / 4));
  cvt_kernel<<<(int)(SZ_W / 4 / 256), 256, 0, stream>>>(Wv_w, wv, (int)(SZ_W / 4));
  cvt_kernel<<<(int)(SZ_W / 4 / 256), 256, 0, stream>>>(Wo_w, wo, (int)(SZ_W / 4));
  // x transpose-convert
  cvtT_kernel<<<dim3(Tt / 64, Cc / 64, Bb), 256, 0, stream>>>(x, xT);

  // fused QK projection: QK[t][o] = sum_c xT[t][c] wqk[o][c] + qkb[o]
  gemm8ph<2, false><<<4 * 8 * Bb, 512, LDSB8, stream>>>(
      xT, wqk, QK, qkb, nullptr,
      Cc, Cc, Cc, 1024, (long)Tt * Cc, 0, (long)Tt * 1024, 4, 8);

  // Vt[o][t] = sum_c Wv[o][c] xT[t][c] + bv[o]
  gemm8p<1, false><<<16 * 2 * Bb, 512, LDSB, stream>>>(
      wv, xT, Vt, Wv_b, nullptr,
      Cc, Cc, Cc, Tt, 0, (long)Tt * Cc, (long)Ci * Tt, 16, 2);

  // Sq[q][kt] = sum_c Q[q][c] K[kt][c]  (+ fused per-kt max)
  gemm8ph<0, true><<<8 * 8 * Bb, 512, LDSB8, stream>>>(
      QK, QK + 512, Sq, nullptr, gmax,
      Ci, 1024, 1024, Tt, (long)Tt * 1024, (long)Tt * 1024, (long)Tt * Tt, 8, 8);

  // E = exp(Sq - m[kt]) in place + per-kt sums
  colsum_kernel<<<dim3(Tt / 256, Tt / 128, Bb), 256, 0, stream>>>(Sq, gmax, sums);

  // fold 1/sum into V
  vscale_kernel<<<(int)(SZ_Q / 8 / 256), 256, 0, stream>>>(Vt, sums);

  // Y[q][c] = sum_kt E[q][kt] Vs[c][kt]
  gemm8p<0, false><<<4 * 8 * Bb, 512, LDSB, stream>>>(
      Sq, Vt, Y, nullptr, nullptr,
      Tt, Tt, Tt, Ci, (long)Tt * Tt, (long)Ci * Tt, (long)Tt * Ci, 4, 8);

  // wy[o][t] = sum_c Wo[o][c] Y[t][c] + bo[o]
  gemm8ph<1, false><<<8 * 4 * Bb, 512, LDSB8, stream>>>(
      wo, Y, wy, Wo_b, nullptr,
      Ci, Ci, Ci, Tt, 0, (long)Tt * Ci, (long)Cc * Tt, 8, 4);

  // BN stats + finalize
  bnstat_kernel<<<Cc, 256, 0, stream>>>(wy, bsum, bsq);
  final_kernel<<<(int)(SZ_XT / 4 / 256), 256, 0, stream>>>(
      wy, x, gamma, beta, bsum, bsq, out);
}

// Round 14
// 280.740 us; speedup vs baseline: 1.0646x; 1.0646x over previous
//
#include <hip/hip_runtime.h>
#include <hip/hip_fp16.h>

typedef _Float16 f16;
typedef f16 f16x8 __attribute__((ext_vector_type(8)));
typedef f16 f16x4 __attribute__((ext_vector_type(4)));
typedef float f32x4 __attribute__((ext_vector_type(4)));

constexpr int Bb = 8, Cc = 1024, Tt = 2048, Ci = 512;
constexpr float BN_EPS = 1e-5f;

__device__ __forceinline__ void gload16(const f16* g, f16* l) {
  __builtin_amdgcn_global_load_lds(
      (const __attribute__((address_space(1))) void*)g,
      (__attribute__((address_space(3))) void*)l, 16, 0, 0);
}

// ---------------- fused fp32 -> fp16 convert of 4 weight matrices ----------
// dst regions contiguous: wq | wk | wv | wo, each SZ_W halves.
__global__ __launch_bounds__(256)
void cvt4_kernel(const float* __restrict__ s0, const float* __restrict__ s1,
                 const float* __restrict__ s2, const float* __restrict__ s3,
                 f16* __restrict__ dst) {
  const float* srcs[4] = {s0, s1, s2, s3};
  const int region = blockIdx.x >> 9;                 // 512 blocks per region
  const int i = (blockIdx.x & 511) * 256 + threadIdx.x;
  float4 v = *((const float4*)srcs[region] + i);
  f16x4 h;
  h[0] = (f16)v.x; h[1] = (f16)v.y; h[2] = (f16)v.z; h[3] = (f16)v.w;
  *((f16x4*)dst + (long)region * 131072 + i) = h;
}

// ---------------- transpose-convert: x[b][c][t] f32 -> xT[b][t][c] f16 ----
__global__ __launch_bounds__(256)
void cvtT_kernel(const float* __restrict__ x, f16* __restrict__ xT) {
  __shared__ float tile[64][68];
  const int b = blockIdx.z, c0 = blockIdx.y * 64, t0 = blockIdx.x * 64;
  const int tid = threadIdx.x;
  const float* xp = x + ((long)b * Cc + c0) * Tt + t0;
  {
    int r = tid >> 4, c4 = (tid & 15) * 4;
    #pragma unroll
    for (int it = 0; it < 4; it++) {
      float4 v = *(const float4*)(xp + (long)(r + it * 16) * Tt + c4);
      *(float4*)&tile[r + it * 16][c4] = v;
    }
  }
  __syncthreads();
  f16* op = xT + ((long)b * Tt + t0) * Cc + c0;
  {
    int c8 = (tid & 7) * 8;
    #pragma unroll
    for (int it = 0; it < 2; it++) {
      int t = (tid >> 3) + it * 32;
      f16x8 o;
      #pragma unroll
      for (int jj = 0; jj < 8; jj++) o[jj] = (f16)tile[c8 + jj][t];
      *(f16x8*)(op + (long)t * Cc + c8) = o;
    }
  }
}

// ======== 256x128 BK=32 ring-3 GEMM (r10 base) + XCD swizzle ===============
// C[m][n] = sum_k A[m][k]*B[n][k]; A:[M,K](lda), B:[N,K](ldb), C:[M,N](ldc).
// LDS 24KB/slot x 3 = 72KB (+2KB BN scratch) -> 2 blocks/CU. Counted vmcnt(3)
// steady-state (prefetch dist 2 tiles). XOR involution on stage-src & ds_read.
// BIAS_MODE: 0 none, 1 per-m, 2 per-n. DO_MAX: per-col max -> gmax.
// DO_BN: per-block per-row sum/sumsq partials -> part1/part2 (no atomics).
template<int BIAS_MODE, bool DO_MAX, bool DO_BN>
__global__ __launch_bounds__(512, 2)
void gemm8p(const f16* __restrict__ A, const f16* __restrict__ B,
            f16* __restrict__ C, const float* __restrict__ bias,
            unsigned* __restrict__ gmax,
            float* __restrict__ part1, float* __restrict__ part2,
            int K, int lda, int ldb, int ldc, long sA, long sB, long sC,
            int nx, int ny)
{
  extern __shared__ f16 lds[];
  constexpr int TILE_A = 256 * 32;           // 8192 halves (16 KB)
  constexpr int TILE_B = 128 * 32;           // 4096 halves (8 KB)
  constexpr int TILE   = TILE_A + TILE_B;    // 12288 halves (24 KB)

  // XCD-aware bijective swizzle (grid %8==0), z-major decode
  const int per = gridDim.x >> 3;
  const int nid = (blockIdx.x & 7) * per + (blockIdx.x >> 3);
  const int bz = nid / (nx * ny);
  const int rem = nid - bz * nx * ny;
  const int by = rem / nx, bx = rem - by * nx;

  const int tid = threadIdx.x, lane = tid & 63, wv = tid >> 6;
  const int bm0 = by * 256, bn0 = bx * 128;
  const int wm = (wv >> 1) * 64, wn = (wv & 1) * 64;
  const f16* Ab = A + (long)bz * sA + (long)bm0 * lda;
  const f16* Bt = B + (long)bz * sB + (long)bn0 * ldb;
  C += (long)bz * sC;

  const int r16 = lane & 15, khi = lane >> 4;

  float* lsum = (float*)(lds + 3 * TILE);
  float* lsq  = lsum + 256;
  if (DO_BN && tid < 256) { lsum[tid] = 0.f; lsq[tid] = 0.f; }

  // stage: linear LDS dest (wave-uniform base + lane*16), pre-swizzled src.
  auto stA = [&](int slot, int k0, int r) {
    int L = (r * 512 + tid) * 16;
    int G = L ^ (((L >> 7) & 3) << 4);
    gload16(Ab + (long)(G >> 6) * lda + k0 + ((G & 63) >> 1),
            lds + (long)slot * TILE + (r * 512 + wv * 64) * 8);
  };
  auto stB = [&](int slot, int k0) {
    int L = tid * 16;
    int G = L ^ (((L >> 7) & 3) << 4);
    gload16(Bt + (long)(G >> 6) * ldb + k0 + ((G & 63) >> 1),
            lds + (long)slot * TILE + TILE_A + (wv * 64) * 8);
  };

  f32x4 acc[4][4] = {};
  const int nt = K >> 5;

  // prologue: tiles 0 and 1 (3 loads each)
  stA(0, 0, 0); stA(0, 0, 1); stB(0, 0);
  stA(1, 32, 0); stA(1, 32, 1); stB(1, 32);
  asm volatile("s_waitcnt vmcnt(3)" ::: "memory");   // tile0 landed
  __builtin_amdgcn_s_barrier();

  for (int t = 0; t < nt; t++) {
    const int slot = t % 3;
    const int nslot = (t + 2) % 3;
    const int k2 = (t + 2) << 5;
    const bool st = (t + 2) < nt;
    const char* baseA = (const char*)(lds + (long)slot * TILE);
    const char* baseB = (const char*)(lds + (long)slot * TILE + TILE_A);

    if (st) { stA(nslot, k2, 0); stA(nslot, k2, 1); stB(nslot, k2); }

    f16x8 af[4], bf[4];
    #pragma unroll
    for (int i = 0; i < 4; i++) {
      const int row = wm + i * 16 + r16;
      af[i] = *(const f16x8*)(baseA + (((row << 6) + (khi << 4)) ^ (((row >> 1) & 3) << 4)));
    }
    #pragma unroll
    for (int j = 0; j < 4; j++) {
      const int row = wn + j * 16 + r16;
      bf[j] = *(const f16x8*)(baseB + (((row << 6) + (khi << 4)) ^ (((row >> 1) & 3) << 4)));
    }

    __builtin_amdgcn_s_setprio(1);
    #pragma unroll
    for (int i = 0; i < 4; i++)
      #pragma unroll
      for (int j = 0; j < 4; j++)
        acc[i][j] = __builtin_amdgcn_mfma_f32_16x16x32_f16(af[i], bf[j], acc[i][j], 0, 0, 0);
    __builtin_amdgcn_s_setprio(0);

    __builtin_amdgcn_sched_barrier(0);
    if (st) asm volatile("s_waitcnt vmcnt(3)" ::: "memory");
    else    asm volatile("s_waitcnt vmcnt(0)" ::: "memory");
    __builtin_amdgcn_s_barrier();
  }

  // ---- epilogue (fused per-column max / per-row BN partials) ----
  const int rg = khi * 4;
  float cmx[4] = {-3e38f, -3e38f, -3e38f, -3e38f};
  #pragma unroll
  for (int i = 0; i < 4; i++) {
    const int row0 = bm0 + wm + i * 16 + rg;
    #pragma unroll
    for (int r = 0; r < 4; r++) {
      const int row = row0 + r;
      const float br = (BIAS_MODE == 1) ? bias[row] : 0.0f;
      float s1 = 0.f, s2 = 0.f;
      #pragma unroll
      for (int j = 0; j < 4; j++) {
        const int col = bn0 + wn + j * 16 + r16;
        float v = acc[i][j][r] + ((BIAS_MODE == 2) ? bias[col] : br);
        C[(long)row * ldc + col] = (f16)v;
        if (DO_MAX) cmx[j] = fmaxf(cmx[j], v);
        if (DO_BN) { s1 += v; s2 += v * v; }
      }
      if (DO_BN) {
        #pragma unroll
        for (int off = 1; off < 16; off <<= 1) {
          s1 += __shfl_xor(s1, off);
          s2 += __shfl_xor(s2, off);
        }
        if (r16 == 0) {
          const int rowl = wm + i * 16 + rg + r;
          atomicAdd(&lsum[rowl], s1);
          atomicAdd(&lsq[rowl], s2);
        }
      }
    }
  }
  if (DO_MAX) {
    #pragma unroll
    for (int j = 0; j < 4; j++) {
      float mx = cmx[j];
      mx = fmaxf(mx, __shfl_xor(mx, 16));
      mx = fmaxf(mx, __shfl_xor(mx, 32));
      if (khi == 0) {
        const int col = bn0 + wn + j * 16 + r16;
        unsigned u = __float_as_uint(mx);
        unsigned key = (u & 0x80000000u) ? ~u : (u | 0x80000000u);
        atomicMax(gmax + (long)bz * ldc + col, key);
      }
    }
  }
  if (DO_BN) {
    __syncthreads();
    if (tid < 256) {
      const long idx = ((long)bz * (ny * 256) + bm0 + tid) * nx + bx;
      part1[idx] = lsum[tid];
      part2[idx] = lsq[tid];
    }
  }
}

// ---------------- colsum: E = exp(Sq - m[kt]) in place; sums[kt] += --------
// vectorized: each thread owns 8 consecutive kt, loops 64 q rows (16B/lane).
__global__ __launch_bounds__(256)
void colsum_kernel(f16* __restrict__ E, const unsigned* __restrict__ gmax,
                   float* __restrict__ sums) {
  const int b = blockIdx.z;
  const int kt0 = threadIdx.x * 8;
  const long q0 = (long)blockIdx.y * 64;
  float m[8], s[8];
  #pragma unroll
  for (int j = 0; j < 8; j++) {
    unsigned key = gmax[b * Tt + kt0 + j];
    m[j] = (key & 0x80000000u) ? __uint_as_float(key ^ 0x80000000u)
                               : __uint_as_float(~key);
    s[j] = 0.f;
  }
  f16* p = E + ((long)b * Tt + q0) * Tt + kt0;
  #pragma unroll 4
  for (int q = 0; q < 64; q++) {
    f16x8 v = *(f16x8*)(p + (long)q * Tt);
    f16x8 o;
    #pragma unroll
    for (int j = 0; j < 8; j++) {
      float e = __expf((float)v[j] - m[j]);
      o[j] = (f16)e;
      s[j] += e;
    }
    *(f16x8*)(p + (long)q * Tt) = o;
  }
  #pragma unroll
  for (int j = 0; j < 8; j++) atomicAdd(sums + b * Tt + kt0 + j, s[j]);
}

// ---------------- vscale: Vt[b][c][kt] *= 1/sums[b][kt] (in place) --------
__global__ __launch_bounds__(256)
void vscale_kernel(f16* __restrict__ Vt, const float* __restrict__ sums) {
  long i = ((long)blockIdx.x * 256 + threadIdx.x) * 8;
  int kt = (int)(i & (Tt - 1));
  int b = (int)(i >> 20);                 // Ci*Tt = 2^20
  f16x8 v = *(f16x8*)(Vt + i);
  const float* sp = sums + b * Tt + kt;
  #pragma unroll
  for (int j = 0; j < 8; j++)
    v[j] = (f16)((float)v[j] * __fdividef(1.0f, sp[j]));
  *(f16x8*)(Vt + i) = v;
}

// ---------------- BN partial reduce: bsum/bsq[c] = sum over 128 slots ------
__global__ __launch_bounds__(64)
void bnreduce_kernel(const float* __restrict__ part1,
                     const float* __restrict__ part2,
                     float* __restrict__ bsum, float* __restrict__ bsq) {
  const int c = blockIdx.x, t = threadIdx.x;   // 64 threads, 128 slots
  const long i0 = ((long)(t >> 4) * Cc + c) * 16 + (t & 15);
  const long i1 = ((long)((t + 64) >> 4) * Cc + c) * 16 + ((t + 64) & 15);
  float s1 = part1[i0] + part1[i1];
  float s2 = part2[i0] + part2[i1];
  #pragma unroll
  for (int off = 1; off < 64; off <<= 1) {
    s1 += __shfl_xor(s1, off);
    s2 += __shfl_xor(s2, off);
  }
  if (t == 0) { bsum[c] = s1; bsq[c] = s2; }
}

// ---------------- finalize: BN + residual ----------------------------------
__global__ __launch_bounds__(256)
void final_kernel(const f16* __restrict__ wy, const float* __restrict__ x,
                  const float* __restrict__ gamma, const float* __restrict__ beta,
                  const float* __restrict__ bsum, const float* __restrict__ bsq,
                  float* __restrict__ out)
{
  long i = ((long)blockIdx.x * blockDim.x + threadIdx.x) * 4;
  int c = (int)((i >> 11) & (Cc - 1));
  const float cnt = (float)Bb * (float)Tt;
  float mean = bsum[c] / cnt;
  float var  = bsq[c] / cnt - mean * mean;
  float sc = rsqrtf(var + BN_EPS) * gamma[c];
  float sh = beta[c] - mean * sc;
  f16x4 w = *(const f16x4*)(wy + i);
  float4 xv = *(const float4*)(x + i);
  float4 o;
  o.x = (float)w[0] * sc + sh + xv.x;
  o.y = (float)w[1] * sc + sh + xv.y;
  o.z = (float)w[2] * sc + sh + xv.z;
  o.w = (float)w[3] * sc + sh + xv.w;
  *(float4*)(out + i) = o;
}

// ---------------- host launch ----------------
extern "C" void kernel_launch(void* const* d_in, const int* in_sizes, int n_in,
                              void* d_out, int out_size, void* d_ws, size_t ws_size,
                              hipStream_t stream) {
  const float* x    = (const float*)d_in[0];
  const float* Wq_w = (const float*)d_in[1];
  const float* Wq_b = (const float*)d_in[2];
  const float* Wk_w = (const float*)d_in[3];
  const float* Wk_b = (const float*)d_in[4];
  const float* Wv_w = (const float*)d_in[5];
  const float* Wv_b = (const float*)d_in[6];
  const float* Wo_w = (const float*)d_in[7];
  const float* Wo_b = (const float*)d_in[8];
  const float* gamma = (const float*)d_in[9];
  const float* beta  = (const float*)d_in[10];
  float* out = (float*)d_out;

  constexpr long SZ_XT = (long)Bb * Tt * Cc;   // 16,777,216
  constexpr long SZ_Q  = (long)Bb * Tt * Ci;   // 8,388,608
  constexpr long SZ_S  = (long)Bb * Tt * Tt;   // 33,554,432
  constexpr long SZ_W  = (long)Ci * Cc;        // 524,288

  f16* ws = (f16*)d_ws;
  f16* xT  = ws;                // [B][T][C]  (dead after V-proj)
  f16* QK  = xT + SZ_XT;        // [B][T][1024]: Q cols 0-511, K cols 512-1023
  f16* Vt  = QK + SZ_XT;        // [B][Ci][T]
  f16* Sq  = Vt + SZ_Q;         // [B][Tq][Tk] -> exp'd in place by colsum
  f16* Y   = Sq + SZ_S;         // [B][Tq][Ci]
  f16* wy  = Y + SZ_Q;          // [B][C][T]
  f16* wqk = wy + SZ_XT;        // wq | wk | wv | wo contiguous (4 x SZ_W)
  f16* wv  = wqk + 2 * SZ_W;
  f16* wo  = wv + SZ_W;
  unsigned* gmax = (unsigned*)(wo + SZ_W);     // [B*Tt] encoded col max
  float* sums = (float*)(gmax + (long)Bb * Tt);// [B*Tt]
  float* bsum = sums + (long)Bb * Tt;          // [Cc]
  float* bsq  = bsum + Cc;                     // [Cc]
  float* qkb  = bsq + Cc;                      // [1024] concat bias
  // BN partials overlay dead xT (Wo runs long after V-proj): 2 x 128K floats
  float* part1 = (float*)xT;
  float* part2 = part1 + (long)Bb * Cc * 16;

  constexpr int LDSB    = (256 * 32 + 128 * 32) * 3 * 2;  // 73728 B
  constexpr int LDSB_BN = LDSB + 256 * 2 * 4;             // +2KB scratch
  hipFuncSetAttribute(reinterpret_cast<const void*>(gemm8p<2, false, false>),
                      hipFuncAttributeMaxDynamicSharedMemorySize, LDSB);
  hipFuncSetAttribute(reinterpret_cast<const void*>(gemm8p<1, false, false>),
                      hipFuncAttributeMaxDynamicSharedMemorySize, LDSB);
  hipFuncSetAttribute(reinterpret_cast<const void*>(gemm8p<0, true, false>),
                      hipFuncAttributeMaxDynamicSharedMemorySize, LDSB);
  hipFuncSetAttribute(reinterpret_cast<const void*>(gemm8p<0, false, false>),
                      hipFuncAttributeMaxDynamicSharedMemorySize, LDSB);
  hipFuncSetAttribute(reinterpret_cast<const void*>(gemm8p<1, false, true>),
                      hipFuncAttributeMaxDynamicSharedMemorySize, LDSB_BN);

  // zero accumulators (gmax||sums contiguous)
  hipMemsetAsync(gmax, 0, (long)Bb * Tt * 2 * sizeof(float), stream);
  // concat q/k bias
  hipMemcpyAsync(qkb, Wq_b, Ci * sizeof(float), hipMemcpyDeviceToDevice, stream);
  hipMemcpyAsync(qkb + Ci, Wk_b, Ci * sizeof(float), hipMemcpyDeviceToDevice, stream);

  // weight converts: one dispatch (wq|wk|wv|wo contiguous dst)
  cvt4_kernel<<<2048, 256, 0, stream>>>(Wq_w, Wk_w, Wv_w, Wo_w, wqk);
  // x transpose-convert
  cvtT_kernel<<<dim3(Tt / 64, Cc / 64, Bb), 256, 0, stream>>>(x, xT);

  // fused QK projection: QK[t][o] = sum_c xT[t][c] wqk[o][c] + qkb[o]
  gemm8p<2, false, false><<<8 * 8 * Bb, 512, LDSB, stream>>>(
      xT, wqk, QK, qkb, nullptr, nullptr, nullptr,
      Cc, Cc, Cc, 1024, (long)Tt * Cc, 0, (long)Tt * 1024, 8, 8);

  // Vt[o][t] = sum_c Wv[o][c] xT[t][c] + bv[o]
  gemm8p<1, false, false><<<16 * 2 * Bb, 512, LDSB, stream>>>(
      wv, xT, Vt, Wv_b, nullptr, nullptr, nullptr,
      Cc, Cc, Cc, Tt, 0, (long)Tt * Cc, (long)Ci * Tt, 16, 2);

  // Sq[q][kt] = sum_c Q[q][c] K[kt][c]  (+ fused per-kt max)
  gemm8p<0, true, false><<<16 * 8 * Bb, 512, LDSB, stream>>>(
      QK, QK + 512, Sq, nullptr, gmax, nullptr, nullptr,
      Ci, 1024, 1024, Tt, (long)Tt * 1024, (long)Tt * 1024, (long)Tt * Tt, 16, 8);

  // E = exp(Sq - m[kt]) in place + per-kt sums (vectorized 16B/lane)
  colsum_kernel<<<dim3(1, Tt / 64, Bb), 256, 0, stream>>>(Sq, gmax, sums);

  // fold 1/sum into V
  vscale_kernel<<<(int)(SZ_Q / 8 / 256), 256, 0, stream>>>(Vt, sums);

  // Y[q][c] = sum_kt E[q][kt] Vs[c][kt]
  gemm8p<0, false, false><<<4 * 8 * Bb, 512, LDSB, stream>>>(
      Sq, Vt, Y, nullptr, nullptr, nullptr, nullptr,
      Tt, Tt, Tt, Ci, (long)Tt * Tt, (long)Ci * Tt, (long)Tt * Ci, 4, 8);

  // wy[o][t] = sum_c Wo[o][c] Y[t][c] + bo[o]  (+ fused BN partials)
  gemm8p<1, false, true><<<16 * 4 * Bb, 512, LDSB_BN, stream>>>(
      wo, Y, wy, Wo_b, nullptr, part1, part2,
      Ci, Ci, Ci, Tt, 0, (long)Tt * Ci, (long)Cc * Tt, 16, 4);

  // BN partial reduce + finalize
  bnreduce_kernel<<<Cc, 64, 0, stream>>>(part1, part2, bsum, bsq);
  final_kernel<<<(int)(SZ_XT / 4 / 256), 256, 0, stream>>>(
      wy, x, gamma, beta, bsum, bsq, out);
}

// Round 15
// 272.497 us; speedup vs baseline: 1.0968x; 1.0302x over previous
//
#include <hip/hip_runtime.h>
#include <hip/hip_fp16.h>

typedef _Float16 f16;
typedef f16 f16x8 __attribute__((ext_vector_type(8)));
typedef f16 f16x4 __attribute__((ext_vector_type(4)));
typedef float f32x4 __attribute__((ext_vector_type(4)));

constexpr int Bb = 8, Cc = 1024, Tt = 2048, Ci = 512;
constexpr float BN_EPS = 1e-5f;

__device__ __forceinline__ void gload16(const f16* g, f16* l) {
  __builtin_amdgcn_global_load_lds(
      (const __attribute__((address_space(1))) void*)g,
      (__attribute__((address_space(3))) void*)l, 16, 0, 0);
}

// ---------------- fp32 -> fp16 convert (weights) ----------------
__global__ __launch_bounds__(256)
void cvt_kernel(const float* __restrict__ src, f16* __restrict__ dst, int n4) {
  int i = blockIdx.x * blockDim.x + threadIdx.x;
  if (i < n4) {
    float4 v = *((const float4*)src + i);
    f16x4 h;
    h[0] = (f16)v.x; h[1] = (f16)v.y; h[2] = (f16)v.z; h[3] = (f16)v.w;
    *((f16x4*)dst + i) = h;
  }
}

// ---------------- transpose-convert: x[b][c][t] f32 -> xT[b][t][c] f16 ----
__global__ __launch_bounds__(256)
void cvtT_kernel(const float* __restrict__ x, f16* __restrict__ xT) {
  __shared__ float tile[64][68];
  const int b = blockIdx.z, c0 = blockIdx.y * 64, t0 = blockIdx.x * 64;
  const int tid = threadIdx.x;
  const float* xp = x + ((long)b * Cc + c0) * Tt + t0;
  {
    int r = tid >> 4, c4 = (tid & 15) * 4;
    #pragma unroll
    for (int it = 0; it < 4; it++) {
      float4 v = *(const float4*)(xp + (long)(r + it * 16) * Tt + c4);
      *(float4*)&tile[r + it * 16][c4] = v;
    }
  }
  __syncthreads();
  f16* op = xT + ((long)b * Tt + t0) * Cc + c0;
  {
    int c8 = (tid & 7) * 8;
    #pragma unroll
    for (int it = 0; it < 2; it++) {
      int t = (tid >> 3) + it * 32;
      f16x8 o;
      #pragma unroll
      for (int jj = 0; jj < 8; jj++) o[jj] = (f16)tile[c8 + jj][t];
      *(f16x8*)(op + (long)t * Cc + c8) = o;
    }
  }
}

// ======== 256x128 BK=32 ring-3 GEMM (2 blocks/CU) + XCD swizzle ============
// C[m][n] = sum_k A[m][k]*B[n][k]; A:[M,K](lda), B:[N,K](ldb), C:[M,N](ldc).
// LDS 24KB/slot x 3 = 72KB -> 2 blocks/CU (16 waves, cross-block overlap
// hides the per-tile vmcnt+barrier drain). Counted vmcnt(3) steady-state
// (prefetch distance 2 tiles). XOR involution (slot[5:4] ^= row[8:7]) on
// BOTH stage-source and ds_read.
// BIAS_MODE: 0 none, 1 per-m, 2 per-n. DO_MAX: per-column max -> gmax.
template<int BIAS_MODE, bool DO_MAX>
__global__ __launch_bounds__(512, 2)
void gemm8p(const f16* __restrict__ A, const f16* __restrict__ B,
            f16* __restrict__ C, const float* __restrict__ bias,
            unsigned* __restrict__ gmax,
            int K, int lda, int ldb, int ldc, long sA, long sB, long sC,
            int nx, int ny)
{
  extern __shared__ f16 lds[];
  constexpr int TILE_A = 256 * 32;           // 8192 halves (16 KB)
  constexpr int TILE_B = 128 * 32;           // 4096 halves (8 KB)
  constexpr int TILE   = TILE_A + TILE_B;    // 12288 halves (24 KB)

  // XCD-aware bijective swizzle (grid %8==0), z-major decode
  const int per = gridDim.x >> 3;
  const int nid = (blockIdx.x & 7) * per + (blockIdx.x >> 3);
  const int bz = nid / (nx * ny);
  const int rem = nid - bz * nx * ny;
  const int by = rem / nx, bx = rem - by * nx;

  const int tid = threadIdx.x, lane = tid & 63, wv = tid >> 6;
  const int bm0 = by * 256, bn0 = bx * 128;
  const int wm = (wv >> 1) * 64, wn = (wv & 1) * 64;
  const f16* Ab = A + (long)bz * sA + (long)bm0 * lda;
  const f16* Bt = B + (long)bz * sB + (long)bn0 * ldb;
  C += (long)bz * sC;

  const int r16 = lane & 15, khi = lane >> 4;

  // stage: linear LDS dest (wave-uniform base + lane*16), pre-swizzled src.
  auto stA = [&](int slot, int k0, int r) {
    int L = (r * 512 + tid) * 16;
    int G = L ^ (((L >> 7) & 3) << 4);
    gload16(Ab + (long)(G >> 6) * lda + k0 + ((G & 63) >> 1),
            lds + (long)slot * TILE + (r * 512 + wv * 64) * 8);
  };
  auto stB = [&](int slot, int k0) {
    int L = tid * 16;
    int G = L ^ (((L >> 7) & 3) << 4);
    gload16(Bt + (long)(G >> 6) * ldb + k0 + ((G & 63) >> 1),
            lds + (long)slot * TILE + TILE_A + (wv * 64) * 8);
  };

  f32x4 acc[4][4] = {};
  const int nt = K >> 5;

  // prologue: tiles 0 and 1 (3 loads each)
  stA(0, 0, 0); stA(0, 0, 1); stB(0, 0);
  stA(1, 32, 0); stA(1, 32, 1); stB(1, 32);
  asm volatile("s_waitcnt vmcnt(3)" ::: "memory");   // tile0 landed
  __builtin_amdgcn_s_barrier();

  for (int t = 0; t < nt; t++) {
    const int slot = t % 3;
    const int nslot = (t + 2) % 3;
    const int k2 = (t + 2) << 5;
    const bool st = (t + 2) < nt;
    const char* baseA = (const char*)(lds + (long)slot * TILE);
    const char* baseB = (const char*)(lds + (long)slot * TILE + TILE_A);

    if (st) { stA(nslot, k2, 0); stA(nslot, k2, 1); stB(nslot, k2); }

    f16x8 af[4], bf[4];
    #pragma unroll
    for (int i = 0; i < 4; i++) {
      const int row = wm + i * 16 + r16;
      af[i] = *(const f16x8*)(baseA + (((row << 6) + (khi << 4)) ^ (((row >> 1) & 3) << 4)));
    }
    #pragma unroll
    for (int j = 0; j < 4; j++) {
      const int row = wn + j * 16 + r16;
      bf[j] = *(const f16x8*)(baseB + (((row << 6) + (khi << 4)) ^ (((row >> 1) & 3) << 4)));
    }

    __builtin_amdgcn_s_setprio(1);
    #pragma unroll
    for (int i = 0; i < 4; i++)
      #pragma unroll
      for (int j = 0; j < 4; j++)
        acc[i][j] = __builtin_amdgcn_mfma_f32_16x16x32_f16(af[i], bf[j], acc[i][j], 0, 0, 0);
    __builtin_amdgcn_s_setprio(0);

    __builtin_amdgcn_sched_barrier(0);
    if (st) asm volatile("s_waitcnt vmcnt(3)" ::: "memory");
    else    asm volatile("s_waitcnt vmcnt(0)" ::: "memory");
    __builtin_amdgcn_s_barrier();
  }

  // ---- epilogue (fused per-column max for DO_MAX) ----
  const int rg = khi * 4;
  float cmx[4] = {-3e38f, -3e38f, -3e38f, -3e38f};
  #pragma unroll
  for (int i = 0; i < 4; i++) {
    const int row0 = bm0 + wm + i * 16 + rg;
    #pragma unroll
    for (int r = 0; r < 4; r++) {
      const int row = row0 + r;
      const float br = (BIAS_MODE == 1) ? bias[row] : 0.0f;
      #pragma unroll
      for (int j = 0; j < 4; j++) {
        const int col = bn0 + wn + j * 16 + r16;
        float v = acc[i][j][r] + ((BIAS_MODE == 2) ? bias[col] : br);
        C[(long)row * ldc + col] = (f16)v;
        if (DO_MAX) cmx[j] = fmaxf(cmx[j], v);
      }
    }
  }
  if (DO_MAX) {
    #pragma unroll
    for (int j = 0; j < 4; j++) {
      float mx = cmx[j];
      mx = fmaxf(mx, __shfl_xor(mx, 16));
      mx = fmaxf(mx, __shfl_xor(mx, 32));
      if (khi == 0) {
        const int col = bn0 + wn + j * 16 + r16;
        unsigned u = __float_as_uint(mx);
        unsigned key = (u & 0x80000000u) ? ~u : (u | 0x80000000u);
        atomicMax(gmax + (long)bz * ldc + col, key);
      }
    }
  }
}

// ---------------- colsum v3: E = exp(Sq - m[kt]) in place; partials -------
// Vectorized f16x8 along kt (1KB/wave per instr). Block = 256 thr covers all
// 2048 kt; 32 q-rows per block -> grid (1, 64, B) = 512 blocks (2/CU).
// No global atomics: per-block partial sums -> part[(b*64+qb)*2048 + kt].
__global__ __launch_bounds__(256)
void colsum_kernel(f16* __restrict__ E, const unsigned* __restrict__ gmax,
                   float* __restrict__ part) {
  const int b = blockIdx.z, qb = blockIdx.y;
  const int kt0 = threadIdx.x * 8;
  const long q0 = (long)qb * 32;
  float m[8], s[8];
  #pragma unroll
  for (int j = 0; j < 8; j++) {
    unsigned key = gmax[b * Tt + kt0 + j];
    m[j] = (key & 0x80000000u) ? __uint_as_float(key ^ 0x80000000u)
                               : __uint_as_float(~key);
    s[j] = 0.f;
  }
  f16* p = E + ((long)b * Tt + q0) * Tt + kt0;
  #pragma unroll 4
  for (int q = 0; q < 32; q++) {
    f16x8 v = *(f16x8*)(p + (long)q * Tt);
    f16x8 o;
    #pragma unroll
    for (int j = 0; j < 8; j++) {
      float e = __expf((float)v[j] - m[j]);
      o[j] = (f16)e;
      s[j] += e;
    }
    *(f16x8*)(p + (long)q * Tt) = o;
  }
  float* pp = part + ((long)(b * 64 + qb) * Tt) + kt0;
  *(float4*)pp       = make_float4(s[0], s[1], s[2], s[3]);
  *(float4*)(pp + 4) = make_float4(s[4], s[5], s[6], s[7]);
}

// ---------------- reduce colsum partials: sums[b][kt] = sum_y part --------
__global__ __launch_bounds__(256)
void sumreduce_kernel(const float* __restrict__ part, float* __restrict__ sums) {
  const int idx = blockIdx.x * 256 + threadIdx.x;   // 16384 = Bb*Tt
  const int b = idx >> 11, kt = idx & (Tt - 1);
  const float* pp = part + (long)b * 64 * Tt + kt;
  float s = 0.f;
  #pragma unroll 8
  for (int y = 0; y < 64; y++) s += pp[(long)y * Tt];
  sums[idx] = s;
}

// ---------------- vscale: Vt[b][c][kt] *= 1/sums[b][kt] (in place) --------
__global__ __launch_bounds__(256)
void vscale_kernel(f16* __restrict__ Vt, const float* __restrict__ sums) {
  long i = ((long)blockIdx.x * 256 + threadIdx.x) * 8;
  int kt = (int)(i & (Tt - 1));
  int b = (int)(i >> 20);                 // Ci*Tt = 2^20
  f16x8 v = *(f16x8*)(Vt + i);
  const float* sp = sums + b * Tt + kt;
  #pragma unroll
  for (int j = 0; j < 8; j++)
    v[j] = (f16)((float)v[j] * __fdividef(1.0f, sp[j]));
  *(f16x8*)(Vt + i) = v;
}

// ---------------- BN stats per channel over (b,t) --------------------------
__global__ __launch_bounds__(256)
void bnstat_kernel(const f16* __restrict__ wy, float* __restrict__ bsum,
                   float* __restrict__ bsq) {
  const int c = blockIdx.x, tid = threadIdx.x;
  float s1 = 0.f, s2 = 0.f;
  for (int b = 0; b < Bb; b++) {
    f16x8 v = *((const f16x8*)(wy + ((long)b * Cc + c) * Tt) + tid);
    #pragma unroll
    for (int jj = 0; jj < 8; jj++) { float f = (float)v[jj]; s1 += f; s2 += f * f; }
  }
  #pragma unroll
  for (int off = 1; off < 64; off <<= 1) {
    s1 += __shfl_xor(s1, off);
    s2 += __shfl_xor(s2, off);
  }
  __shared__ float l1[4], l2[4];
  const int w = tid >> 6;
  if ((tid & 63) == 0) { l1[w] = s1; l2[w] = s2; }
  __syncthreads();
  if (tid == 0) {
    bsum[c] = (l1[0] + l1[1]) + (l1[2] + l1[3]);
    bsq[c]  = (l2[0] + l2[1]) + (l2[2] + l2[3]);
  }
}

// ---------------- finalize: BN + residual ----------------------------------
__global__ __launch_bounds__(256)
void final_kernel(const f16* __restrict__ wy, const float* __restrict__ x,
                  const float* __restrict__ gamma, const float* __restrict__ beta,
                  const float* __restrict__ bsum, const float* __restrict__ bsq,
                  float* __restrict__ out)
{
  long i = ((long)blockIdx.x * blockDim.x + threadIdx.x) * 4;
  int c = (int)((i >> 11) & (Cc - 1));
  const float cnt = (float)Bb * (float)Tt;
  float mean = bsum[c] / cnt;
  float var  = bsq[c] / cnt - mean * mean;
  float sc = rsqrtf(var + BN_EPS) * gamma[c];
  float sh = beta[c] - mean * sc;
  f16x4 w = *(const f16x4*)(wy + i);
  float4 xv = *(const float4*)(x + i);
  float4 o;
  o.x = (float)w[0] * sc + sh + xv.x;
  o.y = (float)w[1] * sc + sh + xv.y;
  o.z = (float)w[2] * sc + sh + xv.z;
  o.w = (float)w[3] * sc + sh + xv.w;
  *(float4*)(out + i) = o;
}

// ---------------- host launch ----------------
extern "C" void kernel_launch(void* const* d_in, const int* in_sizes, int n_in,
                              void* d_out, int out_size, void* d_ws, size_t ws_size,
                              hipStream_t stream) {
  const float* x    = (const float*)d_in[0];
  const float* Wq_w = (const float*)d_in[1];
  const float* Wq_b = (const float*)d_in[2];
  const float* Wk_w = (const float*)d_in[3];
  const float* Wk_b = (const float*)d_in[4];
  const float* Wv_w = (const float*)d_in[5];
  const float* Wv_b = (const float*)d_in[6];
  const float* Wo_w = (const float*)d_in[7];
  const float* Wo_b = (const float*)d_in[8];
  const float* gamma = (const float*)d_in[9];
  const float* beta  = (const float*)d_in[10];
  float* out = (float*)d_out;

  constexpr long SZ_XT = (long)Bb * Tt * Cc;   // 16,777,216
  constexpr long SZ_Q  = (long)Bb * Tt * Ci;   // 8,388,608
  constexpr long SZ_S  = (long)Bb * Tt * Tt;   // 33,554,432
  constexpr long SZ_W  = (long)Ci * Cc;        // 524,288

  f16* ws = (f16*)d_ws;
  f16* xT  = ws;                // [B][T][C]  (dead after V-proj)
  f16* QK  = xT + SZ_XT;        // [B][T][1024]: Q cols 0-511, K cols 512-1023
  f16* Vt  = QK + SZ_XT;        // [B][Ci][T]
  f16* Sq  = Vt + SZ_Q;         // [B][Tq][Tk] -> exp'd in place by colsum
  f16* Y   = Sq + SZ_S;         // [B][Tq][Ci]
  f16* wy  = Y + SZ_Q;          // [B][C][T]
  f16* wqk = wy + SZ_XT;        // [1024][1024] stacked Wq||Wk
  f16* wv  = wqk + 2 * SZ_W;
  f16* wo  = wv + SZ_W;
  unsigned* gmax = (unsigned*)(wo + SZ_W);     // [B*Tt] encoded col max
  float* sums = (float*)(gmax + (long)Bb * Tt);// [B*Tt]
  float* bsum = sums + (long)Bb * Tt;          // [Cc]
  float* bsq  = bsum + Cc;                     // [Cc]
  float* qkb  = bsq + Cc;                      // [1024] concat bias
  // colsum partials overlay dead xT (xT dead after V-proj, before QK^T done):
  float* part = (float*)xT;                    // 8*64*2048 floats = 4 MB

  constexpr int LDSB = (256 * 32 + 128 * 32) * 3 * 2; // 73728 B -> 2 blocks/CU
  hipFuncSetAttribute(reinterpret_cast<const void*>(gemm8p<2, false>),
                      hipFuncAttributeMaxDynamicSharedMemorySize, LDSB);
  hipFuncSetAttribute(reinterpret_cast<const void*>(gemm8p<1, false>),
                      hipFuncAttributeMaxDynamicSharedMemorySize, LDSB);
  hipFuncSetAttribute(reinterpret_cast<const void*>(gemm8p<0, true>),
                      hipFuncAttributeMaxDynamicSharedMemorySize, LDSB);
  hipFuncSetAttribute(reinterpret_cast<const void*>(gemm8p<0, false>),
                      hipFuncAttributeMaxDynamicSharedMemorySize, LDSB);

  // zero gmax
  hipMemsetAsync(gmax, 0, (long)Bb * Tt * sizeof(unsigned), stream);
  // concat q/k bias
  hipMemcpyAsync(qkb, Wq_b, Ci * sizeof(float), hipMemcpyDeviceToDevice, stream);
  hipMemcpyAsync(qkb + Ci, Wk_b, Ci * sizeof(float), hipMemcpyDeviceToDevice, stream);

  // weight converts (wq||wk stacked)
  cvt_kernel<<<(int)(SZ_W / 4 / 256), 256, 0, stream>>>(Wq_w, wqk, (int)(SZ_W / 4));
  cvt_kernel<<<(int)(SZ_W / 4 / 256), 256, 0, stream>>>(Wk_w, wqk + SZ_W, (int)(SZ_W / 4));
  cvt_kernel<<<(int)(SZ_W / 4 / 256), 256, 0, stream>>>(Wv_w, wv, (int)(SZ_W / 4));
  cvt_kernel<<<(int)(SZ_W / 4 / 256), 256, 0, stream>>>(Wo_w, wo, (int)(SZ_W / 4));
  // x transpose-convert
  cvtT_kernel<<<dim3(Tt / 64, Cc / 64, Bb), 256, 0, stream>>>(x, xT);

  // fused QK projection: QK[t][o] = sum_c xT[t][c] wqk[o][c] + qkb[o]
  gemm8p<2, false><<<8 * 8 * Bb, 512, LDSB, stream>>>(
      xT, wqk, QK, qkb, nullptr,
      Cc, Cc, Cc, 1024, (long)Tt * Cc, 0, (long)Tt * 1024, 8, 8);

  // Vt[o][t] = sum_c Wv[o][c] xT[t][c] + bv[o]
  gemm8p<1, false><<<16 * 2 * Bb, 512, LDSB, stream>>>(
      wv, xT, Vt, Wv_b, nullptr,
      Cc, Cc, Cc, Tt, 0, (long)Tt * Cc, (long)Ci * Tt, 16, 2);

  // Sq[q][kt] = sum_c Q[q][c] K[kt][c]  (+ fused per-kt max)
  gemm8p<0, true><<<16 * 8 * Bb, 512, LDSB, stream>>>(
      QK, QK + 512, Sq, nullptr, gmax,
      Ci, 1024, 1024, Tt, (long)Tt * 1024, (long)Tt * 1024, (long)Tt * Tt, 16, 8);

  // E = exp(Sq - m[kt]) in place + per-block partial sums (vectorized)
  colsum_kernel<<<dim3(1, 64, Bb), 256, 0, stream>>>(Sq, gmax, part);
  sumreduce_kernel<<<Bb * Tt / 256, 256, 0, stream>>>(part, sums);

  // fold 1/sum into V
  vscale_kernel<<<(int)(SZ_Q / 8 / 256), 256, 0, stream>>>(Vt, sums);

  // Y[q][c] = sum_kt E[q][kt] Vs[c][kt]
  gemm8p<0, false><<<4 * 8 * Bb, 512, LDSB, stream>>>(
      Sq, Vt, Y, nullptr, nullptr,
      Tt, Tt, Tt, Ci, (long)Tt * Tt, (long)Ci * Tt, (long)Tt * Ci, 4, 8);

  // wy[o][t] = sum_c Wo[o][c] Y[t][c] + bo[o]
  gemm8p<1, false><<<16 * 4 * Bb, 512, LDSB, stream>>>(
      wo, Y, wy, Wo_b, nullptr,
      Ci, Ci, Ci, Tt, 0, (long)Tt * Ci, (long)Cc * Tt, 16, 4);

  // BN stats + finalize
  bnstat_kernel<<<Cc, 256, 0, stream>>>(wy, bsum, bsq);
  final_kernel<<<(int)(SZ_XT / 4 / 256), 256, 0, stream>>>(
      wy, x, gamma, beta, bsum, bsq, out);
}